// Round 4
// baseline (358.635 us; speedup 1.0000x reference)
//
#include <hip/hip_runtime.h>
#include <hip/hip_bf16.h>
#include <stdint.h>

#define DDIM 1024
#define NEXP 8
#define SEG  16384   // per-expert token capacity (worst case: every token picks it)

typedef __attribute__((ext_vector_type(8))) short bf16x8;
typedef __attribute__((ext_vector_type(4))) float f32x4;
typedef __attribute__((ext_vector_type(8))) unsigned short u16x8;

__device__ __forceinline__ unsigned short f2bf(float f) {
    union { float f; unsigned int u; } v; v.f = f;
    unsigned int u = v.u;
    return (unsigned short)((u + 0x7FFFu + ((u >> 16) & 1u)) >> 16);
}
__device__ __forceinline__ float bf2f(unsigned short h) {
    union { unsigned int u; float f; } v; v.u = ((unsigned int)h) << 16;
    return v.f;
}

// ---------------- Kernel A (fused): We fp32->bf16 convert + gating/routing ----
// blockIdx.x < 512  : gating blocks (32 tokens each, 8 waves)
// blockIdx.x >= 512 : convert blocks (512 threads x 8 elems)
__global__ __launch_bounds__(512) void prep(
    const float* __restrict__ x, const float* __restrict__ Wg,
    const float* __restrict__ bg, const float* __restrict__ We,
    unsigned short* __restrict__ xb, unsigned short* __restrict__ web,
    int* __restrict__ cnt, int* __restrict__ tok_list,
    float* __restrict__ gate_list) {

    __shared__ int   se[64];   // entry = local_token*2 + slot
    __shared__ float sg[64];

    if (blockIdx.x >= 512) {
        // ---- convert We ----
        size_t idx = ((size_t)(blockIdx.x - 512) * 512 + threadIdx.x) * 8;
        const f32x4* p = (const f32x4*)(We + idx);
        f32x4 a = __builtin_nontemporal_load(p);
        f32x4 b = __builtin_nontemporal_load(p + 1);
        u16x8 h;
        h[0] = f2bf(a[0]); h[1] = f2bf(a[1]); h[2] = f2bf(a[2]); h[3] = f2bf(a[3]);
        h[4] = f2bf(b[0]); h[5] = f2bf(b[1]); h[6] = f2bf(b[2]); h[7] = f2bf(b[3]);
        *(u16x8*)(web + idx) = h;
        return;
    }

    // ---- gating + route + x conversion ----
    int wave = threadIdx.x >> 6, lane = threadIdx.x & 63;
    int tbase = blockIdx.x * 32;

#pragma unroll
    for (int i = 0; i < 4; i++) {
        int lt = wave * 4 + i;
        int t = tbase + lt;
        const float* xr = x + (size_t)t * DDIM;
        int c0 = lane * 16;

        float4 v[4];
#pragma unroll
        for (int j = 0; j < 4; j++) v[j] = ((const float4*)(xr + c0))[j];

        // fused bf16 conversion of x
        u16x8 h0, h1;
        h0[0] = f2bf(v[0].x); h0[1] = f2bf(v[0].y); h0[2] = f2bf(v[0].z); h0[3] = f2bf(v[0].w);
        h0[4] = f2bf(v[1].x); h0[5] = f2bf(v[1].y); h0[6] = f2bf(v[1].z); h0[7] = f2bf(v[1].w);
        h1[0] = f2bf(v[2].x); h1[1] = f2bf(v[2].y); h1[2] = f2bf(v[2].z); h1[3] = f2bf(v[2].w);
        h1[4] = f2bf(v[3].x); h1[5] = f2bf(v[3].y); h1[6] = f2bf(v[3].z); h1[7] = f2bf(v[3].w);
        u16x8* xo = (u16x8*)(xb + (size_t)t * DDIM + c0);
        xo[0] = h0; xo[1] = h1;

        // fp32 gate logits (routing fidelity vs reference)
        float acc[NEXP];
#pragma unroll
        for (int e = 0; e < NEXP; e++) {
            const float4* wg = (const float4*)(Wg + e * DDIM + c0);
            float s = 0.f;
#pragma unroll
            for (int j = 0; j < 4; j++) {
                float4 w = wg[j];
                s += v[j].x * w.x + v[j].y * w.y + v[j].z * w.z + v[j].w * w.w;
            }
            acc[e] = s;
        }
#pragma unroll
        for (int e = 0; e < NEXP; e++) {
#pragma unroll
            for (int o = 32; o > 0; o >>= 1) acc[e] += __shfl_xor(acc[e], o, 64);
        }

        if (lane == 0) {
            float l1 = -1e30f, l2 = -1e30f; int e1 = 0, e2 = 0;
#pragma unroll
            for (int e = 0; e < NEXP; e++) {
                float le = acc[e] + bg[e];
                if (le > l1) { l2 = l1; e2 = e1; l1 = le; e1 = e; }
                else if (le > l2) { l2 = le; e2 = e; }
            }
            float g1 = 1.0f / (1.0f + __expf(l2 - l1));
            float g2 = 1.0f - g1;
            se[lt * 2]     = e1; sg[lt * 2]     = g1;
            se[lt * 2 + 1] = e2; sg[lt * 2 + 1] = g2;
        }
    }
    __syncthreads();

    // one thread per expert: count, reserve range with ONE atomic, scatter.
    if (threadIdx.x < NEXP) {
        int e = threadIdx.x;
        int k = 0;
#pragma unroll 8
        for (int i = 0; i < 64; i++) k += (se[i] == e);
        if (k) {
            int p = atomicAdd(cnt + e, k);
            for (int i = 0; i < 64; i++) {
                if (se[i] == e) {
                    // entry encodes token*2 + slot (slot = i&1)
                    tok_list[e * SEG + p]  = (tbase + (i >> 1)) * 2 + (i & 1);
                    gate_list[e * SEG + p] = sg[i];
                    p++;
                }
            }
        }
    }
}

// ---------------- Kernel C: per-expert gathered GEMM, bf16 MFMA ----------------
// C[row, col] = sum_d xb[token[row], d] * web[e, col, d]  (NT layout)
// 128x128 tile, BK=64, 4 waves in 2x2, 16x16x32 MFMA, XOR-swizzled LDS granules.
// STORE mode: nontemporal bf16 stores of g*(acc+bias) into S[token*2+slot][col].
// Atomic mode (fallback if ws too small): fp32 atomicAdd into out.
template<bool STORE>
__global__ __launch_bounds__(256, 3) void moe_gemm(
    const unsigned short* __restrict__ xb, const unsigned short* __restrict__ web,
    const float* __restrict__ be, const int* __restrict__ cnt,
    const int* __restrict__ tok_list, const float* __restrict__ gate_list,
    unsigned short* __restrict__ Sb, float* __restrict__ outa) {

    // exact-grid: find (expert, m-tile) from flat blockIdx.y via prefix over cnt
    int id = blockIdx.y, e = 0, c = 0;
    while (e < NEXP) {
        c = cnt[e];
        int mt = (c + 127) >> 7;
        if (id < mt) break;
        id -= mt; e++;
    }
    if (e == NEXP) return;
    int m0 = id << 7;
    int n0 = blockIdx.x << 7;

    __shared__ unsigned short lA[128 * 64];   // 16 KB
    __shared__ unsigned short lB[128 * 64];   // 16 KB
    __shared__ int   tok_s[128];
    __shared__ float gate_s[128];

    int tid = threadIdx.x;
    int wave = tid >> 6, lane = tid & 63;

    if (tid < 128) {
        int r = m0 + tid;
        int rc = min(r, c - 1);
        tok_s[tid]  = tok_list[e * SEG + rc];
        gate_s[tid] = (r < c) ? gate_list[e * SEG + rc] : 0.0f;
    }
    __syncthreads();

    // staging: issue t=wave*4+j covers tile rows 8t..8t+7; lane -> (row 8t+lane/8, dst granule lane%8)
    // LDS[row][gd] holds source granule gd ^ (row&7)   (granule = 16B = 8 bf16)
    int rsub = lane >> 3;
    int gsrc = (lane & 7) ^ rsub;

    const unsigned short* agp[4];
    const unsigned short* bgp[4];
#pragma unroll
    for (int j = 0; j < 4; j++) {
        int row = (wave * 4 + j) * 8 + rsub;
        agp[j] = xb + (size_t)(tok_s[row] >> 1) * DDIM + gsrc * 8;
        bgp[j] = web + ((size_t)e << 20) + (size_t)(n0 + row) * DDIM + gsrc * 8;
    }

    f32x4 acc[4][4];
    f32x4 zz = {0.f, 0.f, 0.f, 0.f};
#pragma unroll
    for (int mi = 0; mi < 4; mi++)
#pragma unroll
        for (int ni = 0; ni < 4; ni++) acc[mi][ni] = zz;

    int wm = (wave >> 1) * 64;
    int wn = (wave & 1) * 64;
    int mrow = lane & 15;
    int q = lane >> 4;

    int offA[4], swA[4], offB[4], swB[4];
#pragma unroll
    for (int i = 0; i < 4; i++) {
        int ra = wm + i * 16 + mrow;
        offA[i] = ra * 64; swA[i] = ra & 7;
        int rb = wn + i * 16 + mrow;
        offB[i] = rb * 64; swB[i] = rb & 7;
    }

    for (int kt = 0; kt < 16; kt++) {
        int k0 = kt * 64;
#pragma unroll
        for (int j = 0; j < 4; j++) {
            __builtin_amdgcn_global_load_lds(
                (const __attribute__((address_space(1))) void*)(agp[j] + k0),
                (__attribute__((address_space(3))) void*)(&lA[(wave * 4 + j) * 512]),
                16, 0, 0);
            __builtin_amdgcn_global_load_lds(
                (const __attribute__((address_space(1))) void*)(bgp[j] + k0),
                (__attribute__((address_space(3))) void*)(&lB[(wave * 4 + j) * 512]),
                16, 0, 0);
        }
        __syncthreads();
#pragma unroll
        for (int kh = 0; kh < 2; kh++) {
            int gq = kh * 4 + q;
            bf16x8 af[4], bfr[4];
#pragma unroll
            for (int i = 0; i < 4; i++)
                af[i] = *(const bf16x8*)&lA[offA[i] + ((gq ^ swA[i]) << 3)];
#pragma unroll
            for (int i = 0; i < 4; i++)
                bfr[i] = *(const bf16x8*)&lB[offB[i] + ((gq ^ swB[i]) << 3)];
#pragma unroll
            for (int mi = 0; mi < 4; mi++)
#pragma unroll
                for (int ni = 0; ni < 4; ni++)
                    acc[mi][ni] = __builtin_amdgcn_mfma_f32_16x16x32_bf16(
                        af[mi], bfr[ni], acc[mi][ni], 0, 0, 0);
        }
        __syncthreads();
    }

    // epilogue: D[row=(lane>>4)*4+r][col=lane&15] per 16x16 frag
#pragma unroll
    for (int ni = 0; ni < 4; ni++) {
        int col = n0 + wn + ni * 16 + mrow;
        float bias = be[e * DDIM + col];
#pragma unroll
        for (int mi = 0; mi < 4; mi++) {
#pragma unroll
            for (int r = 0; r < 4; r++) {
                int rl = wm + mi * 16 + q * 4 + r;
                if (m0 + rl < c) {
                    float g = gate_s[rl];
                    float vv = g * (acc[mi][ni][r] + bias);
                    if (STORE) {
                        // scratch row = token*2+slot: nontemporal bf16 store, no RMW
                        unsigned short hv = f2bf(vv);
                        __builtin_nontemporal_store(
                            hv, Sb + (size_t)tok_s[rl] * DDIM + col);
                    } else {
                        atomicAdd(outa + (size_t)(tok_s[rl] >> 1) * DDIM + col, vv);
                    }
                }
            }
        }
    }
}

// ---------------- Kernel D: combine the two slot rows per token ----------------
// out[t] = S[2t] + S[2t+1]; 8 cols per thread, nontemporal throughout.
__global__ void combine(const unsigned short* __restrict__ S, float* __restrict__ out) {
    size_t i = (size_t)blockIdx.x * 256 + threadIdx.x;   // 8-col group index
    size_t t = i >> 7;                                    // 128 groups per row
    size_t g = i & 127;
    const u16x8* r0 = (const u16x8*)(S + t * 2 * DDIM) + g;
    const u16x8* r1 = (const u16x8*)(S + (t * 2 + 1) * DDIM) + g;
    u16x8 a = __builtin_nontemporal_load(r0);
    u16x8 b = __builtin_nontemporal_load(r1);
    f32x4 o0, o1;
#pragma unroll
    for (int k = 0; k < 4; k++) o0[k] = bf2f(a[k]) + bf2f(b[k]);
#pragma unroll
    for (int k = 0; k < 4; k++) o1[k] = bf2f(a[4 + k]) + bf2f(b[4 + k]);
    f32x4* op = (f32x4*)(out + t * DDIM + g * 8);
    __builtin_nontemporal_store(o0, op);
    __builtin_nontemporal_store(o1, op + 1);
}

extern "C" void kernel_launch(void* const* d_in, const int* in_sizes, int n_in,
                              void* d_out, int out_size, void* d_ws, size_t ws_size,
                              hipStream_t stream) {
    const float* x  = (const float*)d_in[0];
    const float* Wg = (const float*)d_in[1];
    const float* bg = (const float*)d_in[2];
    const float* We = (const float*)d_in[3];
    const float* be = (const float*)d_in[4];
    float* out = (float*)d_out;

    char* ws = (char*)d_ws;
    unsigned short* xb  = (unsigned short*)ws;                          // 32 MB
    unsigned short* web = (unsigned short*)(ws + 33554432);             // 16 MB
    int*   tok_list  = (int*)(ws + 33554432 + 16777216);                // 512 KB
    float* gate_list = (float*)(ws + 33554432 + 16777216 + 524288);     // 512 KB
    int*   cnt       = (int*)(ws + 33554432 + 16777216 + 1048576);      // 32 B
    unsigned short* S = (unsigned short*)(ws + 52428800);               // 67.1 MB (bf16 store path)

    const size_t NEED = 52428800ull + (size_t)32768 * DDIM * 2;         // ~119.5 MB

    hipMemsetAsync(cnt, 0, NEXP * sizeof(int), stream);

    // 512 gating blocks + 2048 convert blocks in one dispatch
    prep<<<2560, 512, 0, stream>>>(x, Wg, bg, We, xb, web, cnt, tok_list, gate_list);

    if (ws_size >= NEED) {
        // grid.y = 264: max total m-tiles = 32768/128 + 8 ceil-partials
        moe_gemm<true><<<dim3(8, 264), 256, 0, stream>>>(
            xb, web, be, cnt, tok_list, gate_list, S, nullptr);
        combine<<<8192, 256, 0, stream>>>(S, out);
    } else {
        hipMemsetAsync(d_out, 0, (size_t)out_size * sizeof(float), stream);
        moe_gemm<false><<<dim3(8, 264), 256, 0, stream>>>(
            xb, web, be, cnt, tok_list, gate_list, nullptr, out);
    }
}

// Round 5
// 306.688 us; speedup vs baseline: 1.1694x; 1.1694x over previous
//
#include <hip/hip_runtime.h>
#include <hip/hip_bf16.h>
#include <stdint.h>

#define DDIM 1024
#define NEXP 8
#define SEG  16384   // per-expert token capacity (worst case: every token picks it)

typedef __attribute__((ext_vector_type(8))) short bf16x8;
typedef __attribute__((ext_vector_type(4))) float f32x4;
typedef __attribute__((ext_vector_type(8))) unsigned short u16x8;

__device__ __forceinline__ unsigned short f2bf(float f) {
    union { float f; unsigned int u; } v; v.f = f;
    unsigned int u = v.u;
    return (unsigned short)((u + 0x7FFFu + ((u >> 16) & 1u)) >> 16);
}
__device__ __forceinline__ float bf2f(unsigned short h) {
    union { unsigned int u; float f; } v; v.u = ((unsigned int)h) << 16;
    return v.f;
}

// ---------------- Kernel A (fused): We fp32->bf16 convert + gating/routing ----
// blockIdx.x < 512  : gating blocks (32 tokens each, 8 waves)
// blockIdx.x >= 512 : convert blocks (512 threads x 8 elems)
__global__ __launch_bounds__(512) void prep(
    const float* __restrict__ x, const float* __restrict__ Wg,
    const float* __restrict__ bg, const float* __restrict__ We,
    unsigned short* __restrict__ xb, unsigned short* __restrict__ web,
    int* __restrict__ cnt, int* __restrict__ tok_list,
    float* __restrict__ gate_list) {

    __shared__ int   se[64];   // entry = local_token*2 + slot
    __shared__ float sg[64];

    if (blockIdx.x >= 512) {
        // ---- convert We ----
        size_t idx = ((size_t)(blockIdx.x - 512) * 512 + threadIdx.x) * 8;
        const f32x4* p = (const f32x4*)(We + idx);
        f32x4 a = __builtin_nontemporal_load(p);
        f32x4 b = __builtin_nontemporal_load(p + 1);
        u16x8 h;
        h[0] = f2bf(a[0]); h[1] = f2bf(a[1]); h[2] = f2bf(a[2]); h[3] = f2bf(a[3]);
        h[4] = f2bf(b[0]); h[5] = f2bf(b[1]); h[6] = f2bf(b[2]); h[7] = f2bf(b[3]);
        *(u16x8*)(web + idx) = h;
        return;
    }

    // ---- gating + route + x conversion ----
    int wave = threadIdx.x >> 6, lane = threadIdx.x & 63;
    int tbase = blockIdx.x * 32;

#pragma unroll
    for (int i = 0; i < 4; i++) {
        int lt = wave * 4 + i;
        int t = tbase + lt;
        const float* xr = x + (size_t)t * DDIM;
        int c0 = lane * 16;

        float4 v[4];
#pragma unroll
        for (int j = 0; j < 4; j++) v[j] = ((const float4*)(xr + c0))[j];

        // fused bf16 conversion of x
        u16x8 h0, h1;
        h0[0] = f2bf(v[0].x); h0[1] = f2bf(v[0].y); h0[2] = f2bf(v[0].z); h0[3] = f2bf(v[0].w);
        h0[4] = f2bf(v[1].x); h0[5] = f2bf(v[1].y); h0[6] = f2bf(v[1].z); h0[7] = f2bf(v[1].w);
        h1[0] = f2bf(v[2].x); h1[1] = f2bf(v[2].y); h1[2] = f2bf(v[2].z); h1[3] = f2bf(v[2].w);
        h1[4] = f2bf(v[3].x); h1[5] = f2bf(v[3].y); h1[6] = f2bf(v[3].z); h1[7] = f2bf(v[3].w);
        u16x8* xo = (u16x8*)(xb + (size_t)t * DDIM + c0);
        xo[0] = h0; xo[1] = h1;

        // fp32 gate logits (routing fidelity vs reference)
        float acc[NEXP];
#pragma unroll
        for (int e = 0; e < NEXP; e++) {
            const float4* wg = (const float4*)(Wg + e * DDIM + c0);
            float s = 0.f;
#pragma unroll
            for (int j = 0; j < 4; j++) {
                float4 w = wg[j];
                s += v[j].x * w.x + v[j].y * w.y + v[j].z * w.z + v[j].w * w.w;
            }
            acc[e] = s;
        }
#pragma unroll
        for (int e = 0; e < NEXP; e++) {
#pragma unroll
            for (int o = 32; o > 0; o >>= 1) acc[e] += __shfl_xor(acc[e], o, 64);
        }

        if (lane == 0) {
            float l1 = -1e30f, l2 = -1e30f; int e1 = 0, e2 = 0;
#pragma unroll
            for (int e = 0; e < NEXP; e++) {
                float le = acc[e] + bg[e];
                if (le > l1) { l2 = l1; e2 = e1; l1 = le; e1 = e; }
                else if (le > l2) { l2 = le; e2 = e; }
            }
            float g1 = 1.0f / (1.0f + __expf(l2 - l1));
            float g2 = 1.0f - g1;
            se[lt * 2]     = e1; sg[lt * 2]     = g1;
            se[lt * 2 + 1] = e2; sg[lt * 2 + 1] = g2;
        }
    }
    __syncthreads();

    // one thread per expert: count, reserve range with ONE atomic, scatter.
    if (threadIdx.x < NEXP) {
        int e = threadIdx.x;
        int k = 0;
#pragma unroll 8
        for (int i = 0; i < 64; i++) k += (se[i] == e);
        if (k) {
            int p = atomicAdd(cnt + e, k);
            for (int i = 0; i < 64; i++) {
                if (se[i] == e) {
                    // entry encodes token*2 + slot (slot = i&1)
                    tok_list[e * SEG + p]  = (tbase + (i >> 1)) * 2 + (i & 1);
                    gate_list[e * SEG + p] = sg[i];
                    p++;
                }
            }
        }
    }
}

// ---------------- Kernel C: per-expert gathered GEMM, bf16 MFMA ----------------
// C[row, col] = sum_d xb[token[row], d] * web[e, col, d]  (NT layout)
// 128x128 tile, BK=64, 4 waves in 2x2, 16x16x32 MFMA, XOR-swizzled LDS granules.
// STORE mode: C-tile staged through LDS (reusing lA/lB) then written as
// coalesced 16B bf16 vector stores into S[token*2+slot][col] — plain stores so
// L2 write-combines and combine() can hit L2/L3.
// Atomic mode (fallback if ws too small): fp32 atomicAdd into out.
template<bool STORE>
__global__ __launch_bounds__(256, 3) void moe_gemm(
    const unsigned short* __restrict__ xb, const unsigned short* __restrict__ web,
    const float* __restrict__ be, const int* __restrict__ cnt,
    const int* __restrict__ tok_list, const float* __restrict__ gate_list,
    unsigned short* __restrict__ Sb, float* __restrict__ outa) {

    // exact-grid: find (expert, m-tile) from flat blockIdx.y via prefix over cnt
    int id = blockIdx.y, e = 0, c = 0;
    while (e < NEXP) {
        c = cnt[e];
        int mt = (c + 127) >> 7;
        if (id < mt) break;
        id -= mt; e++;
    }
    if (e == NEXP) return;
    int m0 = id << 7;
    int n0 = blockIdx.x << 7;

    __shared__ __align__(16) unsigned short lAB[16384];  // lA | lB, reused as C-tile
    unsigned short* lA = lAB;
    unsigned short* lB = lAB + 8192;
    __shared__ int   tok_s[128];
    __shared__ float gate_s[128];

    int tid = threadIdx.x;
    int wave = tid >> 6, lane = tid & 63;

    if (tid < 128) {
        int r = m0 + tid;
        int rc = min(r, c - 1);
        tok_s[tid]  = tok_list[e * SEG + rc];
        gate_s[tid] = (r < c) ? gate_list[e * SEG + rc] : 0.0f;
    }
    __syncthreads();

    // staging: issue t=wave*4+j covers tile rows 8t..8t+7; lane -> (row 8t+lane/8, dst granule lane%8)
    // LDS[row][gd] holds source granule gd ^ (row&7)   (granule = 16B = 8 bf16)
    int rsub = lane >> 3;
    int gsrc = (lane & 7) ^ rsub;

    const unsigned short* agp[4];
    const unsigned short* bgp[4];
#pragma unroll
    for (int j = 0; j < 4; j++) {
        int row = (wave * 4 + j) * 8 + rsub;
        agp[j] = xb + (size_t)(tok_s[row] >> 1) * DDIM + gsrc * 8;
        bgp[j] = web + ((size_t)e << 20) + (size_t)(n0 + row) * DDIM + gsrc * 8;
    }

    f32x4 acc[4][4];
    f32x4 zz = {0.f, 0.f, 0.f, 0.f};
#pragma unroll
    for (int mi = 0; mi < 4; mi++)
#pragma unroll
        for (int ni = 0; ni < 4; ni++) acc[mi][ni] = zz;

    int wm = (wave >> 1) * 64;
    int wn = (wave & 1) * 64;
    int mrow = lane & 15;
    int q = lane >> 4;

    int offA[4], swA[4], offB[4], swB[4];
#pragma unroll
    for (int i = 0; i < 4; i++) {
        int ra = wm + i * 16 + mrow;
        offA[i] = ra * 64; swA[i] = ra & 7;
        int rb = wn + i * 16 + mrow;
        offB[i] = rb * 64; swB[i] = rb & 7;
    }

    for (int kt = 0; kt < 16; kt++) {
        int k0 = kt * 64;
#pragma unroll
        for (int j = 0; j < 4; j++) {
            __builtin_amdgcn_global_load_lds(
                (const __attribute__((address_space(1))) void*)(agp[j] + k0),
                (__attribute__((address_space(3))) void*)(&lA[(wave * 4 + j) * 512]),
                16, 0, 0);
            __builtin_amdgcn_global_load_lds(
                (const __attribute__((address_space(1))) void*)(bgp[j] + k0),
                (__attribute__((address_space(3))) void*)(&lB[(wave * 4 + j) * 512]),
                16, 0, 0);
        }
        __syncthreads();
#pragma unroll
        for (int kh = 0; kh < 2; kh++) {
            int gq = kh * 4 + q;
            bf16x8 af[4], bfr[4];
#pragma unroll
            for (int i = 0; i < 4; i++)
                af[i] = *(const bf16x8*)&lA[offA[i] + ((gq ^ swA[i]) << 3)];
#pragma unroll
            for (int i = 0; i < 4; i++)
                bfr[i] = *(const bf16x8*)&lB[offB[i] + ((gq ^ swB[i]) << 3)];
#pragma unroll
            for (int mi = 0; mi < 4; mi++)
#pragma unroll
                for (int ni = 0; ni < 4; ni++)
                    acc[mi][ni] = __builtin_amdgcn_mfma_f32_16x16x32_bf16(
                        af[mi], bfr[ni], acc[mi][ni], 0, 0, 0);
        }
        __syncthreads();
    }

    if (STORE) {
        // ---- stage C-tile (gate*(acc+bias), bf16) into LDS, XOR-swizzled ----
        // elem addr = row*128 + ((colgranule ^ (row&7))<<3) + (col&7)
#pragma unroll
        for (int ni = 0; ni < 4; ni++) {
            int col = wn + ni * 16 + mrow;           // tile-local col
            float bias = be[e * DDIM + n0 + col];
            int cg = col >> 3, cl = col & 7;
#pragma unroll
            for (int mi = 0; mi < 4; mi++) {
#pragma unroll
                for (int r = 0; r < 4; r++) {
                    int row = wm + mi * 16 + q * 4 + r;
                    float vv = gate_s[row] * (acc[mi][ni][r] + bias);
                    lAB[row * 128 + ((cg ^ (row & 7)) << 3) + cl] = f2bf(vv);
                }
            }
        }
        __syncthreads();
        // ---- coalesced 16B stores: 2048 granules / 256 threads = 8 iters ----
#pragma unroll
        for (int j = 0; j < 8; j++) {
            int t = j * 256 + tid;
            int row = t >> 4, gc = t & 15;
            u16x8 vv = *(const u16x8*)&lAB[row * 128 + ((gc ^ (row & 7)) << 3)];
            if (m0 + row < c)
                *(u16x8*)(Sb + (size_t)tok_s[row] * DDIM + n0 + gc * 8) = vv;
        }
    } else {
        // atomic fallback: D[row=(lane>>4)*4+r][col=lane&15] per 16x16 frag
#pragma unroll
        for (int ni = 0; ni < 4; ni++) {
            int col = n0 + wn + ni * 16 + mrow;
            float bias = be[e * DDIM + col];
#pragma unroll
            for (int mi = 0; mi < 4; mi++) {
#pragma unroll
                for (int r = 0; r < 4; r++) {
                    int rl = wm + mi * 16 + q * 4 + r;
                    if (m0 + rl < c) {
                        float g = gate_s[rl];
                        atomicAdd(outa + (size_t)(tok_s[rl] >> 1) * DDIM + col,
                                  g * (acc[mi][ni][r] + bias));
                    }
                }
            }
        }
    }
}

// ---------------- Kernel D: combine the two slot rows per token ----------------
// out[t] = S[2t] + S[2t+1]; 8 cols per thread; plain loads (S may be L2/L3-hot),
// nontemporal stores for out (never re-read on device).
__global__ void combine(const unsigned short* __restrict__ S, float* __restrict__ out) {
    size_t i = (size_t)blockIdx.x * 256 + threadIdx.x;   // 8-col group index
    size_t t = i >> 7;                                    // 128 groups per row
    size_t g = i & 127;
    const u16x8* r0 = (const u16x8*)(S + t * 2 * DDIM) + g;
    const u16x8* r1 = (const u16x8*)(S + (t * 2 + 1) * DDIM) + g;
    u16x8 a = *r0;
    u16x8 b = *r1;
    f32x4 o0, o1;
#pragma unroll
    for (int k = 0; k < 4; k++) o0[k] = bf2f(a[k]) + bf2f(b[k]);
#pragma unroll
    for (int k = 0; k < 4; k++) o1[k] = bf2f(a[4 + k]) + bf2f(b[4 + k]);
    f32x4* op = (f32x4*)(out + t * DDIM + g * 8);
    __builtin_nontemporal_store(o0, op);
    __builtin_nontemporal_store(o1, op + 1);
}

extern "C" void kernel_launch(void* const* d_in, const int* in_sizes, int n_in,
                              void* d_out, int out_size, void* d_ws, size_t ws_size,
                              hipStream_t stream) {
    const float* x  = (const float*)d_in[0];
    const float* Wg = (const float*)d_in[1];
    const float* bg = (const float*)d_in[2];
    const float* We = (const float*)d_in[3];
    const float* be = (const float*)d_in[4];
    float* out = (float*)d_out;

    char* ws = (char*)d_ws;
    unsigned short* xb  = (unsigned short*)ws;                          // 32 MB
    unsigned short* web = (unsigned short*)(ws + 33554432);             // 16 MB
    int*   tok_list  = (int*)(ws + 33554432 + 16777216);                // 512 KB
    float* gate_list = (float*)(ws + 33554432 + 16777216 + 524288);     // 512 KB
    int*   cnt       = (int*)(ws + 33554432 + 16777216 + 1048576);      // 32 B
    unsigned short* S = (unsigned short*)(ws + 52428800);               // 67.1 MB (bf16 store path)

    const size_t NEED = 52428800ull + (size_t)32768 * DDIM * 2;         // ~119.5 MB

    hipMemsetAsync(cnt, 0, NEXP * sizeof(int), stream);

    // 512 gating blocks + 2048 convert blocks in one dispatch
    prep<<<2560, 512, 0, stream>>>(x, Wg, bg, We, xb, web, cnt, tok_list, gate_list);

    if (ws_size >= NEED) {
        // grid.y = 264: max total m-tiles = 32768/128 + 8 ceil-partials
        moe_gemm<true><<<dim3(8, 264), 256, 0, stream>>>(
            xb, web, be, cnt, tok_list, gate_list, S, nullptr);
        combine<<<8192, 256, 0, stream>>>(S, out);
    } else {
        hipMemsetAsync(d_out, 0, (size_t)out_size * sizeof(float), stream);
        moe_gemm<false><<<dim3(8, 264), 256, 0, stream>>>(
            xb, web, be, cnt, tok_list, gate_list, nullptr, out);
    }
}